// Round 9
// baseline (1273.514 us; speedup 1.0000x reference)
//
#include <hip/hip_runtime.h>
#include <hip/hip_bf16.h>
#include <hip/hip_fp16.h>

typedef unsigned short u16;
typedef unsigned int u32;
typedef short s16x8 __attribute__((ext_vector_type(8)));
typedef float f32x4 __attribute__((ext_vector_type(4)));

#define FE_LD 2944
#define EDGE_LD 2816

static __device__ __forceinline__ float fsig(float x) {
  return __builtin_amdgcn_rcpf(1.f + __expf(-x));
}
static __device__ __forceinline__ float ftanh(float x) {
  return 1.f - 2.f * __builtin_amdgcn_rcpf(1.f + __expf(2.f * x));
}

#define GLD_LDS16(gsrc, ldst) \
  __builtin_amdgcn_global_load_lds((const __attribute__((address_space(1))) void*)(gsrc), \
                                   (__attribute__((address_space(3))) void*)(ldst), 16, 0, 0)

// ---------------------------------------------------------------------------
// Generic bf16 MFMA GEMM: C[M=4096][N] = A[M][K] * B^T[N][K] (+bias), K%64==0.
// 128x128 tile, 4 waves (2x2), 4x4 frags of 16x16x32.
// Staging: global_load_lds width=16, linear LDS dest + pre-swizzled source.
// ---------------------------------------------------------------------------
__global__ __launch_bounds__(256) void gemm_kernel(
    const u16* __restrict__ A, int lda,
    const u16* __restrict__ B, int ldb,
    int K, int N,
    float* __restrict__ outF, __hip_bfloat16* __restrict__ outB, int ldc,
    const float* __restrict__ bias)
{
  __shared__ __align__(16) u16 As[128*64];
  __shared__ __align__(16) u16 Bs[128*64];
  const int tid = threadIdx.x;
  const int w = tid >> 6, lane = tid & 63;
  const int wm = w >> 1, wn = w & 1;
  const long bm = (long)blockIdx.x * 128;
  const long bn = (long)blockIdx.y * 128;
  f32x4 acc[4][4] = {};

  for (int k0 = 0; k0 < K; k0 += 64) {
    #pragma unroll
    for (int rr = 0; rr < 4; rr++) {
      int idx = rr * 256 + tid;
      int row = idx >> 3;
      int g   = idx & 7;
      int gs  = g ^ (row & 7);                 // pre-swizzled source group
      int ldst = (rr * 256 + (w << 6)) * 8;    // linear wave-uniform dest (elems)
      GLD_LDS16(A + (bm + row) * (long)lda + k0 + gs * 8, &As[ldst]);
      GLD_LDS16(B + (bn + row) * (long)ldb + k0 + gs * 8, &Bs[ldst]);
    }
    __syncthreads();
    #pragma unroll
    for (int kk = 0; kk < 2; kk++) {
      s16x8 af[4], bfr[4];
      #pragma unroll
      for (int i = 0; i < 4; i++) {
        int ra = wm * 64 + i * 16 + (lane & 15);
        int rb = wn * 64 + i * 16 + (lane & 15);
        int gg = kk * 4 + (lane >> 4);
        af[i]  = *(const s16x8*)&As[ra * 64 + ((gg ^ (ra & 7)) << 3)];
        bfr[i] = *(const s16x8*)&Bs[rb * 64 + ((gg ^ (rb & 7)) << 3)];
      }
      #pragma unroll
      for (int i = 0; i < 4; i++)
        #pragma unroll
        for (int j = 0; j < 4; j++)
          acc[i][j] = __builtin_amdgcn_mfma_f32_16x16x32_bf16(af[i], bfr[j], acc[i][j], 0, 0, 0);
    }
    __syncthreads();
  }

  #pragma unroll
  for (int i = 0; i < 4; i++)
    #pragma unroll
    for (int j = 0; j < 4; j++)
      #pragma unroll
      for (int v = 0; v < 4; v++) {
        long rr = bm + wm * 64 + i * 16 + (lane >> 4) * 4 + v;
        int  cc = (int)bn + wn * 64 + j * 16 + (lane & 15);
        if (cc < N) {
          float val = acc[i][j][v] + (bias ? bias[cc] : 0.f);
          if (outF) outF[rr * (long)ldc + cc] = val;
          else      outB[rr * (long)ldc + cc] = __float2bfloat16(val);
        }
      }
}

// ---------------------------------------------------------------------------
// Tiled transpose + cast fp32 -> bf16, zero pad, optional row remap.
// dst[n][k] = src[srck][n]
// ---------------------------------------------------------------------------
__global__ void transpose_cast(const float* __restrict__ src, __hip_bfloat16* __restrict__ dst,
                               int srcK, int srcN, int dstR, int dstC, int split, int split_off)
{
  __shared__ float tile[32][33];
  const int kt = blockIdx.x * 32, nt = blockIdx.y * 32;
  const int tx = threadIdx.x & 31, ty = threadIdx.x >> 5;
  for (int i = ty; i < 32; i += 8) {
    int k = kt + i;
    int srck = (k < split) ? (split_off + k) : (k - split);
    int n = nt + tx;
    tile[i][tx] = (srck < srcK && n < srcN) ? src[(size_t)srck * srcN + n] : 0.f;
  }
  __syncthreads();
  for (int i = ty; i < 32; i += 8) {
    int n = nt + i, k = kt + tx;
    if (n < dstR && k < dstC)
      dst[(size_t)n * dstC + k] = __float2bfloat16(tile[tx][i]);
  }
}

// ---------------------------------------------------------------------------
// Quantize whh fp32 [2][256][1024] -> i8 with per-gate-column scale.
//   wreg[(d*32+i)*1024 + col]            : u32 of k {4i..4i+3}, i in [0,32)
//   wlds[((d*8+q)*1024+col)*4 + s]       : u32 of k {128+16q+4s ..}, q<8,s<4
//   wsc [d*1024 + col]                   : maxabs/(127*127) — un-scales BOTH
//                                          the w-quant (127/max) and h-quant (127)
// 2048 threads, one per (d, col).
// ---------------------------------------------------------------------------
__global__ void pack_whh(const float* __restrict__ whh, u32* __restrict__ wreg,
                         u32* __restrict__ wlds, float* __restrict__ wsc)
{
  const int idx = blockIdx.x * 256 + threadIdx.x;   // 0..2047
  const int d = idx >> 10, col = idx & 1023;
  const float* s = whh + (size_t)d * 256 * 1024 + col;
  float mx = 0.f;
  for (int k = 0; k < 256; k++) mx = fmaxf(mx, fabsf(s[(size_t)k * 1024]));
  float inv = (mx > 0.f) ? 127.f / mx : 0.f;
  wsc[d * 1024 + col] = (mx > 0.f) ? mx / (127.f * 127.f) : 0.f;
  for (int i = 0; i < 64; i++) {
    u32 v = 0;
    #pragma unroll
    for (int b = 0; b < 4; b++) {
      int q = __float2int_rn(s[(size_t)(4 * i + b) * 1024] * inv);
      q = max(-127, min(127, q));
      v |= ((u32)(q & 0xff)) << (8 * b);
    }
    if (i < 32) {
      wreg[(size_t)(d * 32 + i) * 1024 + col] = v;
    } else {
      int q8 = (i - 32) >> 2, sb = (i - 32) & 3;
      wlds[((size_t)(d * 8 + q8) * 1024 + col) * 4 + sb] = v;
    }
  }
}

// ---------------------------------------------------------------------------
// prep: softmax(151), probs->bf16 (padded 192), conf=max(probs[1:]),
// pos = relu(BN(center_size(boxes)) @ pos_w + pos_b), fmaps -> FE bf16.
// FE layout: [enc 0..512 | fmaps 512..2560 | embed 2560..2760 | pos 2760..2888 | pad]
// ---------------------------------------------------------------------------
__global__ void prep_kernel(
    const float* __restrict__ logits, const float* __restrict__ fmaps,
    const float* __restrict__ boxes,
    const float* __restrict__ bn_g, const float* __restrict__ bn_b,
    const float* __restrict__ bn_m, const float* __restrict__ bn_v,
    const float* __restrict__ pos_w, const float* __restrict__ pos_b,
    __hip_bfloat16* __restrict__ FE, __hip_bfloat16* __restrict__ probsb,
    float* __restrict__ conf)
{
  __shared__ float red[256];
  const int row = blockIdx.x, t = threadIdx.x;
  float v = (t < 151) ? logits[(size_t)row * 151 + t] : -3.0e38f;
  red[t] = v; __syncthreads();
  for (int s = 128; s > 0; s >>= 1) { if (t < s) red[t] = fmaxf(red[t], red[t + s]); __syncthreads(); }
  float mx = red[0]; __syncthreads();
  float p = (t < 151) ? expf(v - mx) : 0.f;
  red[t] = p; __syncthreads();
  for (int s = 128; s > 0; s >>= 1) { if (t < s) red[t] += red[t + s]; __syncthreads(); }
  float sum = red[0]; __syncthreads();
  p = p / sum;
  if (t < 192) probsb[(size_t)row * 192 + t] = __float2bfloat16((t < 151) ? p : 0.f);
  red[t] = (t >= 1 && t < 151) ? p : 0.f; __syncthreads();
  for (int s = 128; s > 0; s >>= 1) { if (t < s) red[t] = fmaxf(red[t], red[t + s]); __syncthreads(); }
  if (t == 0) conf[row] = red[0];

  if (t < 128) {
    float x1 = boxes[row * 4 + 0], y1 = boxes[row * 4 + 1];
    float x2 = boxes[row * 4 + 2], y2 = boxes[row * 4 + 3];
    float cs[4] = { (x1 + x2) * 0.5f, (y1 + y2) * 0.5f, x2 - x1, y2 - y1 };
    float a = pos_b[t];
    #pragma unroll
    for (int j = 0; j < 4; j++) {
      float cn = (cs[j] - bn_m[j]) * rsqrtf(bn_v[j] + 1e-5f) * bn_g[j] + bn_b[j];
      a += cn * pos_w[j * 128 + t];
    }
    FE[(size_t)row * FE_LD + 2760 + t] = __float2bfloat16(fmaxf(a, 0.f));
  }
  for (int c0 = t; c0 < 2048; c0 += 256)
    FE[(size_t)row * FE_LD + 512 + c0] = __float2bfloat16(fmaps[(size_t)row * 2048 + c0]);
}

// ---------------------------------------------------------------------------
// Per-image bitonic sort of conf desc (tie: index asc) -> perm (global rows).
// ---------------------------------------------------------------------------
__global__ void sort_kernel(const float* __restrict__ conf, int* __restrict__ perm)
{
  __shared__ float key[128];
  __shared__ int   idx[128];
  const int b = blockIdx.x, t = threadIdx.x;
  key[t] = conf[b * 128 + t]; idx[t] = t;
  __syncthreads();
  for (int k = 2; k <= 128; k <<= 1)
    for (int j = k >> 1; j > 0; j >>= 1) {
      int ixj = t ^ j;
      if (ixj > t) {
        bool up = (t & k) == 0;
        float ka = key[t], kb = key[ixj];
        int ia = idx[t], ib = idx[ixj];
        bool before = (ka > kb) || (ka == kb && ia < ib); // desc, stable
        if (before != up) { key[t] = kb; key[ixj] = ka; idx[t] = ib; idx[ixj] = ia; }
      }
      __syncthreads();
    }
  perm[b * 128 + t] = b * 128 + idx[t];
}

// ---------------------------------------------------------------------------
// LSTM scan, i8 weights. 64 blocks = (img 32) x (dir 2), 1024 threads.
// Thread c owns gate column c (full k=256): 32 weight u32 in registers +
// 32 u32 in LDS (128 KB). h broadcast via ONE ds_read_b32 (lane l = h-word l)
// + v_readlane->SGPR per sdot4 (VOP3P allows 1 SGPR operand) — replaces 16
// wave-uniform b128 LDS reads per thread per step.
// ---------------------------------------------------------------------------
__global__ __launch_bounds__(1024) void rec_kernel(
    const float* __restrict__ P,          // [4096][2048] pre-activations (+bias)
    const int* __restrict__ perm,         // [4096] global rows
    const u32* __restrict__ wreg_g,       // [2][32][1024]
    const u32* __restrict__ wlds_g,       // [2][8][1024][4]
    const float* __restrict__ wsc_g,      // [2][1024]
    int gatherPerm, int outPerm,
    __hip_bfloat16* __restrict__ out_bf, int out_ld,
    float* __restrict__ out_f32, int f32_ld, int f32_off)
{
  __shared__ __align__(16) u32 wt[8 * 1024 * 4];   // 128 KB (k 128..255)
  __shared__ float garr[1024];                     // 4 KB gate pre-acts
  __shared__ __align__(16) u32 hq[64];             // 256 i8 of h
  __shared__ int prow_lds[128];
  const int tid = threadIdx.x;
  const int lane = tid & 63;
  const int img = blockIdx.x & 31, dir = blockIdx.x >> 5;

  u32 wv[32];
  {
    const u32* rp = wreg_g + (size_t)dir * 32768 + tid;
    #pragma unroll
    for (int i = 0; i < 32; i++) wv[i] = rp[(size_t)i * 1024];
  }
  #pragma unroll
  for (int i = 0; i < 32; i++) asm volatile("" : "+v"(wv[i]));   // forbid remat
  {
    const uint4* lp = (const uint4*)wlds_g + (size_t)dir * 8192 + tid;
    uint4* wt4 = (uint4*)wt;
    #pragma unroll
    for (int q = 0; q < 8; q++) wt4[q * 1024 + tid] = lp[(size_t)q * 1024];
  }
  const float sc = wsc_g[dir * 1024 + tid];
  if (tid < 128) prow_lds[tid] = perm[img * 128 + tid];
  if (tid < 64) hq[tid] = 0;
  float cst = 0.f;
  __syncthreads();

  const uint4* wt4 = (const uint4*)wt;

  int st = dir ? 127 : 0;
  int prow0 = gatherPerm ? prow_lds[st] : (img * 128 + st);
  float pcur = P[(size_t)prow0 * 2048 + dir * 1024 + tid];

  for (int t = 0; t < 128; t++) {
    float pnext = 0.f;
    if (t < 127) {
      int stn = dir ? (126 - t) : (t + 1);
      int prn = gatherPerm ? prow_lds[stn] : (img * 128 + stn);
      pnext = P[(size_t)prn * 2048 + dir * 1024 + tid];
    }

    u32 hword = hq[lane];        // lane l holds h-word l (one ds_read_b32)
    int a0 = 0, a1 = 0, a2 = 0, a3 = 0;
    #pragma unroll
    for (int q = 0; q < 8; q++) {              // k 0..127 : register weights
      a0 = __builtin_amdgcn_sdot4((int)__builtin_amdgcn_readlane(hword, 4 * q + 0),
                                  (int)wv[4 * q + 0], a0, false);
      a1 = __builtin_amdgcn_sdot4((int)__builtin_amdgcn_readlane(hword, 4 * q + 1),
                                  (int)wv[4 * q + 1], a1, false);
      a2 = __builtin_amdgcn_sdot4((int)__builtin_amdgcn_readlane(hword, 4 * q + 2),
                                  (int)wv[4 * q + 2], a2, false);
      a3 = __builtin_amdgcn_sdot4((int)__builtin_amdgcn_readlane(hword, 4 * q + 3),
                                  (int)wv[4 * q + 3], a3, false);
    }
    #pragma unroll
    for (int q = 0; q < 8; q++) {              // k 128..255 : LDS weights
      uint4 wl = wt4[q * 1024 + tid];
      a0 = __builtin_amdgcn_sdot4((int)__builtin_amdgcn_readlane(hword, 32 + 4 * q + 0),
                                  (int)wl.x, a0, false);
      a1 = __builtin_amdgcn_sdot4((int)__builtin_amdgcn_readlane(hword, 32 + 4 * q + 1),
                                  (int)wl.y, a1, false);
      a2 = __builtin_amdgcn_sdot4((int)__builtin_amdgcn_readlane(hword, 32 + 4 * q + 2),
                                  (int)wl.z, a2, false);
      a3 = __builtin_amdgcn_sdot4((int)__builtin_amdgcn_readlane(hword, 32 + 4 * q + 3),
                                  (int)wl.w, a3, false);
    }
    garr[tid] = pcur + (float)((a0 + a1) + (a2 + a3)) * sc;
    __syncthreads();

    if (tid < 256) {
      float gi = garr[tid], gf = garr[256 + tid], gg = garr[512 + tid], go = garr[768 + tid];
      float si = fsig(gi), sf = fsig(gf), so = fsig(go);
      cst = sf * cst + si * ftanh(gg);
      float h = so * ftanh(cst);
      int qi = __float2int_rn(h * 127.f);
      ((signed char*)hq)[tid] = (signed char)qi;
      const int orow = outPerm ? prow_lds[st] : (img * 128 + st);
      if (out_bf)  out_bf[(size_t)orow * out_ld + dir * 256 + tid] = __float2bfloat16(h);
      if (out_f32) out_f32[(size_t)orow * f32_ld + f32_off + dir * 256 + tid] = h;
    }
    __syncthreads();
    pcur = pnext;
    st = dir ? (st - 1) : (st + 1);
  }
}

// ---------------------------------------------------------------------------
// argmax over obj_dists[:,1:151) -> preds (first max wins, like jnp.argmax)
// ---------------------------------------------------------------------------
__global__ void argmax_kernel(const float* __restrict__ dists, int* __restrict__ preds)
{
  const int row = blockIdx.x * 4 + (threadIdx.x >> 6);
  const int lane = threadIdx.x & 63;
  float best = -3.4e38f; int bi = 1000;
  for (int cc = 1 + lane; cc < 151; cc += 64) {
    float v = dists[(size_t)row * 663 + cc];
    if (v > best) { best = v; bi = cc; }
  }
  for (int off = 32; off > 0; off >>= 1) {
    float ov = __shfl_down(best, off);
    int   oi = __shfl_down(bi, off);
    if (ov > best || (ov == best && oi < bi)) { best = ov; bi = oi; }
  }
  if (lane == 0) preds[row] = bi;
}

// ---------------------------------------------------------------------------
// edge_in = [embed2[pred] (200) | enc (512, from FE) | fmaps (2048)] bf16
// ---------------------------------------------------------------------------
__global__ void edge_build(const int* __restrict__ preds,
                           const float* __restrict__ embed2,
                           const float* __restrict__ fmaps,
                           const __hip_bfloat16* __restrict__ FE,
                           __hip_bfloat16* __restrict__ EDGE)
{
  const int row = blockIdx.x, t = threadIdx.x;
  const int pr = preds[row];
  for (int c0 = t; c0 < 200; c0 += 256)
    EDGE[(size_t)row * EDGE_LD + c0] = __float2bfloat16(embed2[(size_t)pr * 200 + c0]);
  for (int c0 = t; c0 < 512; c0 += 256)
    EDGE[(size_t)row * EDGE_LD + 200 + c0] = FE[(size_t)row * FE_LD + c0];
  for (int c0 = t; c0 < 2048; c0 += 256)
    EDGE[(size_t)row * EDGE_LD + 712 + c0] = __float2bfloat16(fmaps[(size_t)row * 2048 + c0]);
}

// ---------------------------------------------------------------------------
extern "C" void kernel_launch(void* const* d_in, const int* in_sizes, int n_in,
                              void* d_out, int out_size, void* d_ws, size_t ws_size,
                              hipStream_t stream)
{
  const float* obj_fmaps    = (const float*)d_in[0];
  const float* obj_logits   = (const float*)d_in[1];
  const float* boxes        = (const float*)d_in[2];
  const float* obj_embed_w  = (const float*)d_in[4];
  const float* obj_embed2_w = (const float*)d_in[5];
  const float* bn_g = (const float*)d_in[6];
  const float* bn_b = (const float*)d_in[7];
  const float* bn_m = (const float*)d_in[8];
  const float* bn_v = (const float*)d_in[9];
  const float* pos_w = (const float*)d_in[10];
  const float* pos_b = (const float*)d_in[11];
  const float* obj_wih0 = (const float*)d_in[12];
  const float* obj_whh0 = (const float*)d_in[13];
  const float* obj_b0   = (const float*)d_in[14];
  const float* obj_wih1 = (const float*)d_in[15];
  const float* obj_whh1 = (const float*)d_in[16];
  const float* obj_b1   = (const float*)d_in[17];
  const float* edge_wih0 = (const float*)d_in[18];
  const float* edge_whh0 = (const float*)d_in[19];
  const float* edge_b0   = (const float*)d_in[20];
  const float* edge_wih1 = (const float*)d_in[21];
  const float* edge_whh1 = (const float*)d_in[22];
  const float* edge_b1   = (const float*)d_in[23];
  const float* dec_w = (const float*)d_in[24];
  const float* dec_b = (const float*)d_in[25];
  float* out = (float*)d_out;

  char* ws = (char*)d_ws;
  auto alloc = [&](size_t bytes) -> char* {
    char* p = ws; ws += (bytes + 255) & ~(size_t)255; return p;
  };
  __hip_bfloat16* FE     = (__hip_bfloat16*)alloc(4096ull * FE_LD * 2);
  __hip_bfloat16* EDGE   = (__hip_bfloat16*)alloc(4096ull * EDGE_LD * 2);
  float*          Pbuf   = (float*)alloc(4096ull * 2048 * 4);
  __hip_bfloat16* hseq   = (__hip_bfloat16*)alloc(4096ull * 512 * 2);
  __hip_bfloat16* probsb = (__hip_bfloat16*)alloc(4096ull * 192 * 2);
  __hip_bfloat16* wih0T  = (__hip_bfloat16*)alloc(2048ull * 2432 * 2);
  __hip_bfloat16* wih1T  = (__hip_bfloat16*)alloc(2048ull * 512 * 2);
  __hip_bfloat16* ewih0T = (__hip_bfloat16*)alloc(2048ull * 2816 * 2);
  __hip_bfloat16* ewih1T = (__hip_bfloat16*)alloc(2048ull * 512 * 2);
  __hip_bfloat16* embedT = (__hip_bfloat16*)alloc(256ull * 192 * 2);
  __hip_bfloat16* decT   = (__hip_bfloat16*)alloc(256ull * 2944 * 2);
  // packed whh set: wreg 65536 u32 | wlds 65536 u32 | wsc 2048 f32
  u32* whh0pk  = (u32*)alloc(133120ull * 4);
  u32* whh1pk  = (u32*)alloc(133120ull * 4);
  u32* ewhh0pk = (u32*)alloc(133120ull * 4);
  u32* ewhh1pk = (u32*)alloc(133120ull * 4);
  int*   perm  = (int*)alloc(4096 * 4);
  float* conf  = (float*)alloc(4096 * 4);
  int*   preds = (int*)alloc(4096 * 4);
  (void)in_sizes; (void)n_in; (void)out_size; (void)ws_size;

  auto tr = [&](const float* src, __hip_bfloat16* dst, int srcK, int srcN,
                int dstR, int dstC, int split, int soff) {
    dim3 g((dstC + 31) / 32, (dstR + 31) / 32);
    transpose_cast<<<g, dim3(256), 0, stream>>>(src, dst, srcK, srcN, dstR, dstC, split, soff);
  };
  for (int d = 0; d < 2; d++) {
    tr(obj_wih0 + (size_t)d * 2376 * 1024, wih0T + (size_t)d * 1024 * 2432, 2376, 1024, 1024, 2432, 0, 0);
    tr(obj_wih1 + (size_t)d * 512 * 1024,  wih1T + (size_t)d * 1024 * 512,  512, 1024, 1024, 512, 0, 0);
    tr(edge_wih0 + (size_t)d * 2760 * 1024, ewih0T + (size_t)d * 1024 * 2816, 2760, 1024, 1024, 2816, 0, 0);
    tr(edge_wih1 + (size_t)d * 512 * 1024,  ewih1T + (size_t)d * 1024 * 512,  512, 1024, 1024, 512, 0, 0);
  }
  tr(obj_embed_w, embedT, 151, 200, 256, 192, 0, 0);
  tr(dec_w, decT, 2888, 151, 256, 2944, 512, 2376);  // [enc|feats] ordering remap

  auto pk = [&](const float* whh, u32* dst) {
    pack_whh<<<dim3(8), dim3(256), 0, stream>>>(whh, dst, dst + 65536, (float*)(dst + 131072));
  };
  pk(obj_whh0, whh0pk); pk(obj_whh1, whh1pk); pk(edge_whh0, ewhh0pk); pk(edge_whh1, ewhh1pk);

  prep_kernel<<<dim3(4096), dim3(256), 0, stream>>>(
      obj_logits, obj_fmaps, boxes, bn_g, bn_b, bn_m, bn_v, pos_w, pos_b, FE, probsb, conf);
  sort_kernel<<<dim3(32), dim3(128), 0, stream>>>(conf, perm);

  auto gemm = [&](const void* A, int lda, const void* B, int ldb, int K, int N,
                  float* oF, __hip_bfloat16* oB, int ldc, const float* bias) {
    dim3 g(32, (N + 127) / 128);
    gemm_kernel<<<g, dim3(256), 0, stream>>>(
        (const u16*)A, lda, (const u16*)B, ldb, K, N, oF, oB, ldc, bias);
  };
  auto rec = [&](const float* P, const u32* wpk, int gat, int op,
                 __hip_bfloat16* ob, int old_, float* of, int fld, int foff) {
    rec_kernel<<<dim3(64), dim3(1024), 0, stream>>>(
        P, perm, wpk, wpk + 65536, (const float*)(wpk + 131072),
        gat, op, ob, old_, of, fld, foff);
  };

  // obj_embed -> FE cols [2560,2760)
  gemm(probsb, 192, embedT, 192, 192, 200, nullptr, FE + 2560, FE_LD, nullptr);
  // obj layer 0
  gemm((const u16*)FE + 512, FE_LD, wih0T, 2432, 2432, 2048, Pbuf, nullptr, 2048, obj_b0);
  rec(Pbuf, whh0pk, 1, 0, hseq, 512, nullptr, 0, 0);
  // obj layer 1 -> enc into FE cols [0,512)
  gemm(hseq, 512, wih1T, 512, 512, 2048, Pbuf, nullptr, 2048, obj_b1);
  rec(Pbuf, whh1pk, 0, 1, FE, FE_LD, nullptr, 0, 0);
  // decoder -> out cols [0,151)
  gemm(FE, FE_LD, decT, 2944, 2944, 151, out, nullptr, 663, dec_b);
  argmax_kernel<<<dim3(1024), dim3(256), 0, stream>>>(out, preds);
  edge_build<<<dim3(4096), dim3(256), 0, stream>>>(preds, obj_embed2_w, obj_fmaps, FE, EDGE);
  // edge layer 0
  gemm(EDGE, EDGE_LD, ewih0T, 2816, 2816, 2048, Pbuf, nullptr, 2048, edge_b0);
  rec(Pbuf, ewhh0pk, 1, 0, hseq, 512, nullptr, 0, 0);
  // edge layer 1 -> out cols [151,663)
  gemm(hseq, 512, ewih1T, 512, 512, 2048, Pbuf, nullptr, 2048, edge_b1);
  rec(Pbuf, ewhh1pk, 0, 1, nullptr, 0, out, 663, 151);
}

// Round 10
// 1129.138 us; speedup vs baseline: 1.1279x; 1.1279x over previous
//
#include <hip/hip_runtime.h>
#include <hip/hip_bf16.h>
#include <hip/hip_fp16.h>

typedef unsigned short u16;
typedef unsigned int u32;
typedef short s16x8 __attribute__((ext_vector_type(8)));
typedef float f32x4 __attribute__((ext_vector_type(4)));

#define FE_LD 2944
#define EDGE_LD 2816

static __device__ __forceinline__ int sdot4(u32 a, u32 b, int acc) {
  return __builtin_amdgcn_sdot4((int)a, (int)b, acc, false);
}
static __device__ __forceinline__ float fsig(float x) {
  return __builtin_amdgcn_rcpf(1.f + __expf(-x));
}
static __device__ __forceinline__ float ftanh(float x) {
  return 1.f - 2.f * __builtin_amdgcn_rcpf(1.f + __expf(2.f * x));
}

#define GLD_LDS16(gsrc, ldst) \
  __builtin_amdgcn_global_load_lds((const __attribute__((address_space(1))) void*)(gsrc), \
                                   (__attribute__((address_space(3))) void*)(ldst), 16, 0, 0)

// ---------------------------------------------------------------------------
// Generic bf16 MFMA GEMM: C[M=4096][N] = A[M][K] * B^T[N][K] (+bias), K%64==0.
// 128x128 tile, 4 waves (2x2), 4x4 frags of 16x16x32.
// Staging: global_load_lds width=16, linear LDS dest + pre-swizzled source.
// ---------------------------------------------------------------------------
__global__ __launch_bounds__(256) void gemm_kernel(
    const u16* __restrict__ A, int lda,
    const u16* __restrict__ B, int ldb,
    int K, int N,
    float* __restrict__ outF, __hip_bfloat16* __restrict__ outB, int ldc,
    const float* __restrict__ bias)
{
  __shared__ __align__(16) u16 As[128*64];
  __shared__ __align__(16) u16 Bs[128*64];
  const int tid = threadIdx.x;
  const int w = tid >> 6, lane = tid & 63;
  const int wm = w >> 1, wn = w & 1;
  const long bm = (long)blockIdx.x * 128;
  const long bn = (long)blockIdx.y * 128;
  f32x4 acc[4][4] = {};

  for (int k0 = 0; k0 < K; k0 += 64) {
    #pragma unroll
    for (int rr = 0; rr < 4; rr++) {
      int idx = rr * 256 + tid;
      int row = idx >> 3;
      int g   = idx & 7;
      int gs  = g ^ (row & 7);                 // pre-swizzled source group
      int ldst = (rr * 256 + (w << 6)) * 8;    // linear wave-uniform dest (elems)
      GLD_LDS16(A + (bm + row) * (long)lda + k0 + gs * 8, &As[ldst]);
      GLD_LDS16(B + (bn + row) * (long)ldb + k0 + gs * 8, &Bs[ldst]);
    }
    __syncthreads();
    #pragma unroll
    for (int kk = 0; kk < 2; kk++) {
      s16x8 af[4], bfr[4];
      #pragma unroll
      for (int i = 0; i < 4; i++) {
        int ra = wm * 64 + i * 16 + (lane & 15);
        int rb = wn * 64 + i * 16 + (lane & 15);
        int gg = kk * 4 + (lane >> 4);
        af[i]  = *(const s16x8*)&As[ra * 64 + ((gg ^ (ra & 7)) << 3)];
        bfr[i] = *(const s16x8*)&Bs[rb * 64 + ((gg ^ (rb & 7)) << 3)];
      }
      #pragma unroll
      for (int i = 0; i < 4; i++)
        #pragma unroll
        for (int j = 0; j < 4; j++)
          acc[i][j] = __builtin_amdgcn_mfma_f32_16x16x32_bf16(af[i], bfr[j], acc[i][j], 0, 0, 0);
    }
    __syncthreads();
  }

  #pragma unroll
  for (int i = 0; i < 4; i++)
    #pragma unroll
    for (int j = 0; j < 4; j++)
      #pragma unroll
      for (int v = 0; v < 4; v++) {
        long rr = bm + wm * 64 + i * 16 + (lane >> 4) * 4 + v;
        int  cc = (int)bn + wn * 64 + j * 16 + (lane & 15);
        if (cc < N) {
          float val = acc[i][j][v] + (bias ? bias[cc] : 0.f);
          if (outF) outF[rr * (long)ldc + cc] = val;
          else      outB[rr * (long)ldc + cc] = __float2bfloat16(val);
        }
      }
}

// ---------------------------------------------------------------------------
// Tiled transpose + cast fp32 -> bf16, zero pad, optional row remap.
// dst[n][k] = src[srck][n]
// ---------------------------------------------------------------------------
__global__ void transpose_cast(const float* __restrict__ src, __hip_bfloat16* __restrict__ dst,
                               int srcK, int srcN, int dstR, int dstC, int split, int split_off)
{
  __shared__ float tile[32][33];
  const int kt = blockIdx.x * 32, nt = blockIdx.y * 32;
  const int tx = threadIdx.x & 31, ty = threadIdx.x >> 5;
  for (int i = ty; i < 32; i += 8) {
    int k = kt + i;
    int srck = (k < split) ? (split_off + k) : (k - split);
    int n = nt + tx;
    tile[i][tx] = (srck < srcK && n < srcN) ? src[(size_t)srck * srcN + n] : 0.f;
  }
  __syncthreads();
  for (int i = ty; i < 32; i += 8) {
    int n = nt + i, k = kt + tx;
    if (n < dstR && k < dstC)
      dst[(size_t)n * dstC + k] = __float2bfloat16(tile[tx][i]);
  }
}

// ---------------------------------------------------------------------------
// Quantize whh fp32 [2][256][1024] -> i8, kg-split layout.
// Thread per (d,col): col = c4*256 + j (c4 = gate, j = h-dim).
// For kg 0..3, slot = kg*256+j:
//   w in 0..7  -> wreg[(d*32 + c4*8 + w)*1024 + slot]      (k = kg*64+4w..+3)
//   w in 8..15 -> wlds uint4 [(d*8 + c4*2 + (w-8)/4)*1024 + slot], comp (w-8)&3
//   wsc[d*1024+col] = maxabs/(127*127)  (un-scales w-quant AND h-quant)
// ---------------------------------------------------------------------------
__global__ void pack_whh(const float* __restrict__ whh, u32* __restrict__ wreg,
                         u32* __restrict__ wlds, float* __restrict__ wsc)
{
  const int idx = blockIdx.x * 256 + threadIdx.x;   // 0..2047
  const int d = idx >> 10, col = idx & 1023;
  const int c4 = col >> 8, j = col & 255;
  const float* s = whh + (size_t)d * 256 * 1024 + col;
  float mx = 0.f;
  for (int k = 0; k < 256; k++) mx = fmaxf(mx, fabsf(s[(size_t)k * 1024]));
  float inv = (mx > 0.f) ? 127.f / mx : 0.f;
  wsc[d * 1024 + col] = (mx > 0.f) ? mx / (127.f * 127.f) : 0.f;
  for (int kg = 0; kg < 4; kg++) {
    const int slot = kg * 256 + j;
    for (int w = 0; w < 16; w++) {
      u32 v = 0;
      #pragma unroll
      for (int b = 0; b < 4; b++) {
        int q = __float2int_rn(s[(size_t)(kg * 64 + 4 * w + b) * 1024] * inv);
        q = max(-127, min(127, q));
        v |= ((u32)(q & 0xff)) << (8 * b);
      }
      if (w < 8)
        wreg[(size_t)(d * 32 + c4 * 8 + w) * 1024 + slot] = v;
      else
        wlds[((size_t)(d * 8 + c4 * 2 + ((w - 8) >> 2)) * 1024 + slot) * 4 + ((w - 8) & 3)] = v;
    }
  }
}

// ---------------------------------------------------------------------------
// prep: softmax(151), probs->bf16 (padded 192), conf=max(probs[1:]),
// pos = relu(BN(center_size(boxes)) @ pos_w + pos_b), fmaps -> FE bf16.
// FE layout: [enc 0..512 | fmaps 512..2560 | embed 2560..2760 | pos 2760..2888 | pad]
// ---------------------------------------------------------------------------
__global__ void prep_kernel(
    const float* __restrict__ logits, const float* __restrict__ fmaps,
    const float* __restrict__ boxes,
    const float* __restrict__ bn_g, const float* __restrict__ bn_b,
    const float* __restrict__ bn_m, const float* __restrict__ bn_v,
    const float* __restrict__ pos_w, const float* __restrict__ pos_b,
    __hip_bfloat16* __restrict__ FE, __hip_bfloat16* __restrict__ probsb,
    float* __restrict__ conf)
{
  __shared__ float red[256];
  const int row = blockIdx.x, t = threadIdx.x;
  float v = (t < 151) ? logits[(size_t)row * 151 + t] : -3.0e38f;
  red[t] = v; __syncthreads();
  for (int s = 128; s > 0; s >>= 1) { if (t < s) red[t] = fmaxf(red[t], red[t + s]); __syncthreads(); }
  float mx = red[0]; __syncthreads();
  float p = (t < 151) ? expf(v - mx) : 0.f;
  red[t] = p; __syncthreads();
  for (int s = 128; s > 0; s >>= 1) { if (t < s) red[t] += red[t + s]; __syncthreads(); }
  float sum = red[0]; __syncthreads();
  p = p / sum;
  if (t < 192) probsb[(size_t)row * 192 + t] = __float2bfloat16((t < 151) ? p : 0.f);
  red[t] = (t >= 1 && t < 151) ? p : 0.f; __syncthreads();
  for (int s = 128; s > 0; s >>= 1) { if (t < s) red[t] = fmaxf(red[t], red[t + s]); __syncthreads(); }
  if (t == 0) conf[row] = red[0];

  if (t < 128) {
    float x1 = boxes[row * 4 + 0], y1 = boxes[row * 4 + 1];
    float x2 = boxes[row * 4 + 2], y2 = boxes[row * 4 + 3];
    float cs[4] = { (x1 + x2) * 0.5f, (y1 + y2) * 0.5f, x2 - x1, y2 - y1 };
    float a = pos_b[t];
    #pragma unroll
    for (int j = 0; j < 4; j++) {
      float cn = (cs[j] - bn_m[j]) * rsqrtf(bn_v[j] + 1e-5f) * bn_g[j] + bn_b[j];
      a += cn * pos_w[j * 128 + t];
    }
    FE[(size_t)row * FE_LD + 2760 + t] = __float2bfloat16(fmaxf(a, 0.f));
  }
  for (int c0 = t; c0 < 2048; c0 += 256)
    FE[(size_t)row * FE_LD + 512 + c0] = __float2bfloat16(fmaps[(size_t)row * 2048 + c0]);
}

// ---------------------------------------------------------------------------
// Per-image bitonic sort of conf desc (tie: index asc) -> perm (global rows).
// ---------------------------------------------------------------------------
__global__ void sort_kernel(const float* __restrict__ conf, int* __restrict__ perm)
{
  __shared__ float key[128];
  __shared__ int   idx[128];
  const int b = blockIdx.x, t = threadIdx.x;
  key[t] = conf[b * 128 + t]; idx[t] = t;
  __syncthreads();
  for (int k = 2; k <= 128; k <<= 1)
    for (int j = k >> 1; j > 0; j >>= 1) {
      int ixj = t ^ j;
      if (ixj > t) {
        bool up = (t & k) == 0;
        float ka = key[t], kb = key[ixj];
        int ia = idx[t], ib = idx[ixj];
        bool before = (ka > kb) || (ka == kb && ia < ib); // desc, stable
        if (before != up) { key[t] = kb; key[ixj] = ka; idx[t] = ib; idx[ixj] = ia; }
      }
      __syncthreads();
    }
  perm[b * 128 + t] = b * 128 + idx[t];
}

// ---------------------------------------------------------------------------
// LSTM scan, i8 weights, kg-split. 64 blocks = (img 32) x (dir 2), 1024 thr.
// Thread (kg=tid>>8, j=tid&255): int partials of the 4 gates of h-dim j over
// k in [kg*64, kg*64+64). h per thread: 4 b128 broadcasts (vs 16 full-k).
// Weights: 32 u32 resident + 32 u32 LDS. int4 partials in LDS; act threads
// sum 4 kg-partials, apply per-col scale, LSTM cell, re-quantize h to i8.
// ---------------------------------------------------------------------------
__global__ __launch_bounds__(1024) void rec_kernel(
    const float* __restrict__ P,          // [4096][2048] pre-activations (+bias)
    const int* __restrict__ perm,         // [4096] global rows
    const u32* __restrict__ wreg_g,       // [2][32][1024]
    const uint4* __restrict__ wlds_g,     // [2][8][1024]
    const float* __restrict__ wsc_g,      // [2][1024]
    int gatherPerm, int outPerm,
    __hip_bfloat16* __restrict__ out_bf, int out_ld,
    float* __restrict__ out_f32, int f32_ld, int f32_off)
{
  __shared__ __align__(16) uint4 wt4[8 * 1024];    // 128 KB (k tails per col)
  __shared__ __align__(16) int4 part[256 * 4];     // 16 KB  [j][kg]
  __shared__ __align__(16) u32 hq[64];             // 256 i8 of h
  __shared__ int prow_lds[128];
  const int tid = threadIdx.x;
  const int kg = tid >> 8;
  const int img = blockIdx.x & 31, dir = blockIdx.x >> 5;

  u32 wv[32];
  {
    const u32* rp = wreg_g + (size_t)dir * 32768 + tid;
    #pragma unroll
    for (int i = 0; i < 32; i++) wv[i] = rp[(size_t)i * 1024];
  }
  #pragma unroll
  for (int i = 0; i < 32; i++) asm volatile("" : "+v"(wv[i]));   // forbid remat
  {
    const uint4* lp = wlds_g + (size_t)dir * 8192 + tid;
    #pragma unroll
    for (int q = 0; q < 8; q++) wt4[q * 1024 + tid] = lp[(size_t)q * 1024];
  }
  if (tid < 128) prow_lds[tid] = perm[img * 128 + tid];
  if (tid < 64) hq[tid] = 0;

  float sc0 = 0.f, sc1 = 0.f, sc2 = 0.f, sc3 = 0.f, cst = 0.f;
  if (tid < 256) {
    const float* sp = wsc_g + dir * 1024 + tid;
    sc0 = sp[0]; sc1 = sp[256]; sc2 = sp[512]; sc3 = sp[768];
  }
  __syncthreads();

  const uint4* hq4 = (const uint4*)hq;

  int st = dir ? 127 : 0;
  float p0 = 0.f, p1 = 0.f, p2 = 0.f, p3 = 0.f;
  if (tid < 256) {
    int prow0 = gatherPerm ? prow_lds[st] : (img * 128 + st);
    const float* pp = P + (size_t)prow0 * 2048 + dir * 1024 + tid;
    p0 = pp[0]; p1 = pp[256]; p2 = pp[512]; p3 = pp[768];
  }

  for (int t = 0; t < 128; t++) {
    float n0 = 0.f, n1 = 0.f, n2 = 0.f, n3 = 0.f;
    if (tid < 256 && t < 127) {
      int stn = dir ? (126 - t) : (t + 1);
      int prn = gatherPerm ? prow_lds[stn] : (img * 128 + stn);
      const float* pp = P + (size_t)prn * 2048 + dir * 1024 + tid;
      n0 = pp[0]; n1 = pp[256]; n2 = pp[512]; n3 = pp[768];
    }

    int a0 = 0, a1 = 0, a2 = 0, a3 = 0;
    // h words 0..7 of this kg chunk : register weights
    #pragma unroll
    for (int hw = 0; hw < 2; hw++) {
      uint4 hv = hq4[kg * 4 + hw];
      #pragma unroll
      for (int s = 0; s < 4; s++) {
        u32 hp = (s == 0) ? hv.x : (s == 1) ? hv.y : (s == 2) ? hv.z : hv.w;
        int w = hw * 4 + s;
        a0 = sdot4(hp, wv[w], a0);
        a1 = sdot4(hp, wv[8 + w], a1);
        a2 = sdot4(hp, wv[16 + w], a2);
        a3 = sdot4(hp, wv[24 + w], a3);
      }
    }
    // h words 8..15 : LDS weights
    #pragma unroll
    for (int half = 0; half < 2; half++) {
      uint4 hv = hq4[kg * 4 + 2 + half];
      uint4 wl = wt4[(half) * 1024 + tid];
      a0 = sdot4(hv.x, wl.x, a0); a0 = sdot4(hv.y, wl.y, a0);
      a0 = sdot4(hv.z, wl.z, a0); a0 = sdot4(hv.w, wl.w, a0);
      wl = wt4[(2 + half) * 1024 + tid];
      a1 = sdot4(hv.x, wl.x, a1); a1 = sdot4(hv.y, wl.y, a1);
      a1 = sdot4(hv.z, wl.z, a1); a1 = sdot4(hv.w, wl.w, a1);
      wl = wt4[(4 + half) * 1024 + tid];
      a2 = sdot4(hv.x, wl.x, a2); a2 = sdot4(hv.y, wl.y, a2);
      a2 = sdot4(hv.z, wl.z, a2); a2 = sdot4(hv.w, wl.w, a2);
      wl = wt4[(6 + half) * 1024 + tid];
      a3 = sdot4(hv.x, wl.x, a3); a3 = sdot4(hv.y, wl.y, a3);
      a3 = sdot4(hv.z, wl.z, a3); a3 = sdot4(hv.w, wl.w, a3);
    }

    part[(tid & 255) * 4 + kg] = int4{a0, a1, a2, a3};
    __syncthreads();

    if (tid < 256) {
      int4 q0 = part[tid * 4 + 0], q1 = part[tid * 4 + 1];
      int4 q2 = part[tid * 4 + 2], q3 = part[tid * 4 + 3];
      float gi = (float)(q0.x + q1.x + q2.x + q3.x) * sc0 + p0;
      float gf = (float)(q0.y + q1.y + q2.y + q3.y) * sc1 + p1;
      float gg = (float)(q0.z + q1.z + q2.z + q3.z) * sc2 + p2;
      float go = (float)(q0.w + q1.w + q2.w + q3.w) * sc3 + p3;
      float si = fsig(gi), sf = fsig(gf), so = fsig(go);
      cst = sf * cst + si * ftanh(gg);
      float h = so * ftanh(cst);
      int qi = __float2int_rn(h * 127.f);
      ((signed char*)hq)[tid] = (signed char)qi;
      const int orow = outPerm ? prow_lds[st] : (img * 128 + st);
      if (out_bf)  out_bf[(size_t)orow * out_ld + dir * 256 + tid] = __float2bfloat16(h);
      if (out_f32) out_f32[(size_t)orow * f32_ld + f32_off + dir * 256 + tid] = h;
    }
    __syncthreads();
    p0 = n0; p1 = n1; p2 = n2; p3 = n3;
    st = dir ? (st - 1) : (st + 1);
  }
}

// ---------------------------------------------------------------------------
// argmax over obj_dists[:,1:151) -> preds (first max wins, like jnp.argmax)
// ---------------------------------------------------------------------------
__global__ void argmax_kernel(const float* __restrict__ dists, int* __restrict__ preds)
{
  const int row = blockIdx.x * 4 + (threadIdx.x >> 6);
  const int lane = threadIdx.x & 63;
  float best = -3.4e38f; int bi = 1000;
  for (int cc = 1 + lane; cc < 151; cc += 64) {
    float v = dists[(size_t)row * 663 + cc];
    if (v > best) { best = v; bi = cc; }
  }
  for (int off = 32; off > 0; off >>= 1) {
    float ov = __shfl_down(best, off);
    int   oi = __shfl_down(bi, off);
    if (ov > best || (ov == best && oi < bi)) { best = ov; bi = oi; }
  }
  if (lane == 0) preds[row] = bi;
}

// ---------------------------------------------------------------------------
// edge_in = [embed2[pred] (200) | enc (512, from FE) | fmaps (2048)] bf16
// ---------------------------------------------------------------------------
__global__ void edge_build(const int* __restrict__ preds,
                           const float* __restrict__ embed2,
                           const float* __restrict__ fmaps,
                           const __hip_bfloat16* __restrict__ FE,
                           __hip_bfloat16* __restrict__ EDGE)
{
  const int row = blockIdx.x, t = threadIdx.x;
  const int pr = preds[row];
  for (int c0 = t; c0 < 200; c0 += 256)
    EDGE[(size_t)row * EDGE_LD + c0] = __float2bfloat16(embed2[(size_t)pr * 200 + c0]);
  for (int c0 = t; c0 < 512; c0 += 256)
    EDGE[(size_t)row * EDGE_LD + 200 + c0] = FE[(size_t)row * FE_LD + c0];
  for (int c0 = t; c0 < 2048; c0 += 256)
    EDGE[(size_t)row * EDGE_LD + 712 + c0] = __float2bfloat16(fmaps[(size_t)row * 2048 + c0]);
}

// ---------------------------------------------------------------------------
extern "C" void kernel_launch(void* const* d_in, const int* in_sizes, int n_in,
                              void* d_out, int out_size, void* d_ws, size_t ws_size,
                              hipStream_t stream)
{
  const float* obj_fmaps    = (const float*)d_in[0];
  const float* obj_logits   = (const float*)d_in[1];
  const float* boxes        = (const float*)d_in[2];
  const float* obj_embed_w  = (const float*)d_in[4];
  const float* obj_embed2_w = (const float*)d_in[5];
  const float* bn_g = (const float*)d_in[6];
  const float* bn_b = (const float*)d_in[7];
  const float* bn_m = (const float*)d_in[8];
  const float* bn_v = (const float*)d_in[9];
  const float* pos_w = (const float*)d_in[10];
  const float* pos_b = (const float*)d_in[11];
  const float* obj_wih0 = (const float*)d_in[12];
  const float* obj_whh0 = (const float*)d_in[13];
  const float* obj_b0   = (const float*)d_in[14];
  const float* obj_wih1 = (const float*)d_in[15];
  const float* obj_whh1 = (const float*)d_in[16];
  const float* obj_b1   = (const float*)d_in[17];
  const float* edge_wih0 = (const float*)d_in[18];
  const float* edge_whh0 = (const float*)d_in[19];
  const float* edge_b0   = (const float*)d_in[20];
  const float* edge_wih1 = (const float*)d_in[21];
  const float* edge_whh1 = (const float*)d_in[22];
  const float* edge_b1   = (const float*)d_in[23];
  const float* dec_w = (const float*)d_in[24];
  const float* dec_b = (const float*)d_in[25];
  float* out = (float*)d_out;

  char* ws = (char*)d_ws;
  auto alloc = [&](size_t bytes) -> char* {
    char* p = ws; ws += (bytes + 255) & ~(size_t)255; return p;
  };
  __hip_bfloat16* FE     = (__hip_bfloat16*)alloc(4096ull * FE_LD * 2);
  __hip_bfloat16* EDGE   = (__hip_bfloat16*)alloc(4096ull * EDGE_LD * 2);
  float*          Pbuf   = (float*)alloc(4096ull * 2048 * 4);
  __hip_bfloat16* hseq   = (__hip_bfloat16*)alloc(4096ull * 512 * 2);
  __hip_bfloat16* probsb = (__hip_bfloat16*)alloc(4096ull * 192 * 2);
  __hip_bfloat16* wih0T  = (__hip_bfloat16*)alloc(2048ull * 2432 * 2);
  __hip_bfloat16* wih1T  = (__hip_bfloat16*)alloc(2048ull * 512 * 2);
  __hip_bfloat16* ewih0T = (__hip_bfloat16*)alloc(2048ull * 2816 * 2);
  __hip_bfloat16* ewih1T = (__hip_bfloat16*)alloc(2048ull * 512 * 2);
  __hip_bfloat16* embedT = (__hip_bfloat16*)alloc(256ull * 192 * 2);
  __hip_bfloat16* decT   = (__hip_bfloat16*)alloc(256ull * 2944 * 2);
  // packed whh set: wreg 65536 u32 | wlds 65536 u32 | wsc 2048 f32
  u32* whh0pk  = (u32*)alloc(133120ull * 4);
  u32* whh1pk  = (u32*)alloc(133120ull * 4);
  u32* ewhh0pk = (u32*)alloc(133120ull * 4);
  u32* ewhh1pk = (u32*)alloc(133120ull * 4);
  int*   perm  = (int*)alloc(4096 * 4);
  float* conf  = (float*)alloc(4096 * 4);
  int*   preds = (int*)alloc(4096 * 4);
  (void)in_sizes; (void)n_in; (void)out_size; (void)ws_size;

  auto tr = [&](const float* src, __hip_bfloat16* dst, int srcK, int srcN,
                int dstR, int dstC, int split, int soff) {
    dim3 g((dstC + 31) / 32, (dstR + 31) / 32);
    transpose_cast<<<g, dim3(256), 0, stream>>>(src, dst, srcK, srcN, dstR, dstC, split, soff);
  };
  for (int d = 0; d < 2; d++) {
    tr(obj_wih0 + (size_t)d * 2376 * 1024, wih0T + (size_t)d * 1024 * 2432, 2376, 1024, 1024, 2432, 0, 0);
    tr(obj_wih1 + (size_t)d * 512 * 1024,  wih1T + (size_t)d * 1024 * 512,  512, 1024, 1024, 512, 0, 0);
    tr(edge_wih0 + (size_t)d * 2760 * 1024, ewih0T + (size_t)d * 1024 * 2816, 2760, 1024, 1024, 2816, 0, 0);
    tr(edge_wih1 + (size_t)d * 512 * 1024,  ewih1T + (size_t)d * 1024 * 512,  512, 1024, 1024, 512, 0, 0);
  }
  tr(obj_embed_w, embedT, 151, 200, 256, 192, 0, 0);
  tr(dec_w, decT, 2888, 151, 256, 2944, 512, 2376);  // [enc|feats] ordering remap

  auto pk = [&](const float* whh, u32* dst) {
    pack_whh<<<dim3(8), dim3(256), 0, stream>>>(whh, dst, dst + 65536, (float*)(dst + 131072));
  };
  pk(obj_whh0, whh0pk); pk(obj_whh1, whh1pk); pk(edge_whh0, ewhh0pk); pk(edge_whh1, ewhh1pk);

  prep_kernel<<<dim3(4096), dim3(256), 0, stream>>>(
      obj_logits, obj_fmaps, boxes, bn_g, bn_b, bn_m, bn_v, pos_w, pos_b, FE, probsb, conf);
  sort_kernel<<<dim3(32), dim3(128), 0, stream>>>(conf, perm);

  auto gemm = [&](const void* A, int lda, const void* B, int ldb, int K, int N,
                  float* oF, __hip_bfloat16* oB, int ldc, const float* bias) {
    dim3 g(32, (N + 127) / 128);
    gemm_kernel<<<g, dim3(256), 0, stream>>>(
        (const u16*)A, lda, (const u16*)B, ldb, K, N, oF, oB, ldc, bias);
  };
  auto rec = [&](const float* P, const u32* wpk, int gat, int op,
                 __hip_bfloat16* ob, int old_, float* of, int fld, int foff) {
    rec_kernel<<<dim3(64), dim3(1024), 0, stream>>>(
        P, perm, wpk, (const uint4*)(wpk + 65536), (const float*)(wpk + 131072),
        gat, op, ob, old_, of, fld, foff);
  };

  // obj_embed -> FE cols [2560,2760)
  gemm(probsb, 192, embedT, 192, 192, 200, nullptr, FE + 2560, FE_LD, nullptr);
  // obj layer 0
  gemm((const u16*)FE + 512, FE_LD, wih0T, 2432, 2432, 2048, Pbuf, nullptr, 2048, obj_b0);
  rec(Pbuf, whh0pk, 1, 0, hseq, 512, nullptr, 0, 0);
  // obj layer 1 -> enc into FE cols [0,512)
  gemm(hseq, 512, wih1T, 512, 512, 2048, Pbuf, nullptr, 2048, obj_b1);
  rec(Pbuf, whh1pk, 0, 1, FE, FE_LD, nullptr, 0, 0);
  // decoder -> out cols [0,151)
  gemm(FE, FE_LD, decT, 2944, 2944, 151, out, nullptr, 663, dec_b);
  argmax_kernel<<<dim3(1024), dim3(256), 0, stream>>>(out, preds);
  edge_build<<<dim3(4096), dim3(256), 0, stream>>>(preds, obj_embed2_w, obj_fmaps, FE, EDGE);
  // edge layer 0
  gemm(EDGE, EDGE_LD, ewih0T, 2816, 2816, 2048, Pbuf, nullptr, 2048, edge_b0);
  rec(Pbuf, ewhh0pk, 1, 0, hseq, 512, nullptr, 0, 0);
  // edge layer 1 -> out cols [151,663)
  gemm(hseq, 512, ewih1T, 512, 512, 2048, Pbuf, nullptr, 2048, edge_b1);
  rec(Pbuf, ewhh1pk, 0, 1, nullptr, 0, out, 663, 151);
}

// Round 11
// 1007.240 us; speedup vs baseline: 1.2644x; 1.1210x over previous
//
#include <hip/hip_runtime.h>
#include <hip/hip_bf16.h>
#include <hip/hip_fp16.h>

typedef unsigned short u16;
typedef unsigned int u32;
typedef short s16x8 __attribute__((ext_vector_type(8)));
typedef float f32x4 __attribute__((ext_vector_type(4)));

#define FE_LD 2944
#define EDGE_LD 2816

static __device__ __forceinline__ int sdot4(u32 a, u32 b, int acc) {
  return __builtin_amdgcn_sdot4((int)a, (int)b, acc, false);
}
static __device__ __forceinline__ float fsig(float x) {
  return __builtin_amdgcn_rcpf(1.f + __expf(-x));
}
static __device__ __forceinline__ float ftanh(float x) {
  return 1.f - 2.f * __builtin_amdgcn_rcpf(1.f + __expf(2.f * x));
}

#define GLD_LDS16(gsrc, ldst) \
  __builtin_amdgcn_global_load_lds((const __attribute__((address_space(1))) void*)(gsrc), \
                                   (__attribute__((address_space(3))) void*)(ldst), 16, 0, 0)

// ---------------------------------------------------------------------------
// Generic bf16 MFMA GEMM: C[M=4096][N] = A[M][K] * B^T[N][K] (+bias), K%64==0.
// 128x128 tile, 4 waves (2x2), 4x4 frags of 16x16x32.
// Staging: global_load_lds width=16, linear LDS dest + pre-swizzled source.
// ---------------------------------------------------------------------------
__global__ __launch_bounds__(256) void gemm_kernel(
    const u16* __restrict__ A, int lda,
    const u16* __restrict__ B, int ldb,
    int K, int N,
    float* __restrict__ outF, __hip_bfloat16* __restrict__ outB, int ldc,
    const float* __restrict__ bias)
{
  __shared__ __align__(16) u16 As[128*64];
  __shared__ __align__(16) u16 Bs[128*64];
  const int tid = threadIdx.x;
  const int w = tid >> 6, lane = tid & 63;
  const int wm = w >> 1, wn = w & 1;
  const long bm = (long)blockIdx.x * 128;
  const long bn = (long)blockIdx.y * 128;
  f32x4 acc[4][4] = {};

  for (int k0 = 0; k0 < K; k0 += 64) {
    #pragma unroll
    for (int rr = 0; rr < 4; rr++) {
      int idx = rr * 256 + tid;
      int row = idx >> 3;
      int g   = idx & 7;
      int gs  = g ^ (row & 7);                 // pre-swizzled source group
      int ldst = (rr * 256 + (w << 6)) * 8;    // linear wave-uniform dest (elems)
      GLD_LDS16(A + (bm + row) * (long)lda + k0 + gs * 8, &As[ldst]);
      GLD_LDS16(B + (bn + row) * (long)ldb + k0 + gs * 8, &Bs[ldst]);
    }
    __syncthreads();
    #pragma unroll
    for (int kk = 0; kk < 2; kk++) {
      s16x8 af[4], bfr[4];
      #pragma unroll
      for (int i = 0; i < 4; i++) {
        int ra = wm * 64 + i * 16 + (lane & 15);
        int rb = wn * 64 + i * 16 + (lane & 15);
        int gg = kk * 4 + (lane >> 4);
        af[i]  = *(const s16x8*)&As[ra * 64 + ((gg ^ (ra & 7)) << 3)];
        bfr[i] = *(const s16x8*)&Bs[rb * 64 + ((gg ^ (rb & 7)) << 3)];
      }
      #pragma unroll
      for (int i = 0; i < 4; i++)
        #pragma unroll
        for (int j = 0; j < 4; j++)
          acc[i][j] = __builtin_amdgcn_mfma_f32_16x16x32_bf16(af[i], bfr[j], acc[i][j], 0, 0, 0);
    }
    __syncthreads();
  }

  #pragma unroll
  for (int i = 0; i < 4; i++)
    #pragma unroll
    for (int j = 0; j < 4; j++)
      #pragma unroll
      for (int v = 0; v < 4; v++) {
        long rr = bm + wm * 64 + i * 16 + (lane >> 4) * 4 + v;
        int  cc = (int)bn + wn * 64 + j * 16 + (lane & 15);
        if (cc < N) {
          float val = acc[i][j][v] + (bias ? bias[cc] : 0.f);
          if (outF) outF[rr * (long)ldc + cc] = val;
          else      outB[rr * (long)ldc + cc] = __float2bfloat16(val);
        }
      }
}

// ---------------------------------------------------------------------------
// Tiled transpose + cast fp32 -> bf16, zero pad, optional row remap.
// dst[n][k] = src[srck][n]
// ---------------------------------------------------------------------------
__global__ void transpose_cast(const float* __restrict__ src, __hip_bfloat16* __restrict__ dst,
                               int srcK, int srcN, int dstR, int dstC, int split, int split_off)
{
  __shared__ float tile[32][33];
  const int kt = blockIdx.x * 32, nt = blockIdx.y * 32;
  const int tx = threadIdx.x & 31, ty = threadIdx.x >> 5;
  for (int i = ty; i < 32; i += 8) {
    int k = kt + i;
    int srck = (k < split) ? (split_off + k) : (k - split);
    int n = nt + tx;
    tile[i][tx] = (srck < srcK && n < srcN) ? src[(size_t)srck * srcN + n] : 0.f;
  }
  __syncthreads();
  for (int i = ty; i < 32; i += 8) {
    int n = nt + i, k = kt + tx;
    if (n < dstR && k < dstC)
      dst[(size_t)n * dstC + k] = __float2bfloat16(tile[tx][i]);
  }
}

// ---------------------------------------------------------------------------
// Quantize whh fp32 [2][256][1024] -> i8, kg-split layout.
// Thread per (d,col): col = c4*256 + j (c4 = gate, j = h-dim).
// For kg 0..3, slot = kg*256+j:
//   w in 0..7  -> wreg[(d*32 + c4*8 + w)*1024 + slot]      (k = kg*64+4w..+3)
//   w in 8..15 -> wlds uint4 [(d*8 + c4*2 + (w-8)/4)*1024 + slot], comp (w-8)&3
//   wsc[d*1024+col] = maxabs/(127*127)  (un-scales w-quant AND h-quant)
// ---------------------------------------------------------------------------
__global__ void pack_whh(const float* __restrict__ whh, u32* __restrict__ wreg,
                         u32* __restrict__ wlds, float* __restrict__ wsc)
{
  const int idx = blockIdx.x * 256 + threadIdx.x;   // 0..2047
  const int d = idx >> 10, col = idx & 1023;
  const int c4 = col >> 8, j = col & 255;
  const float* s = whh + (size_t)d * 256 * 1024 + col;
  float mx = 0.f;
  for (int k = 0; k < 256; k++) mx = fmaxf(mx, fabsf(s[(size_t)k * 1024]));
  float inv = (mx > 0.f) ? 127.f / mx : 0.f;
  wsc[d * 1024 + col] = (mx > 0.f) ? mx / (127.f * 127.f) : 0.f;
  for (int kg = 0; kg < 4; kg++) {
    const int slot = kg * 256 + j;
    for (int w = 0; w < 16; w++) {
      u32 v = 0;
      #pragma unroll
      for (int b = 0; b < 4; b++) {
        int q = __float2int_rn(s[(size_t)(kg * 64 + 4 * w + b) * 1024] * inv);
        q = max(-127, min(127, q));
        v |= ((u32)(q & 0xff)) << (8 * b);
      }
      if (w < 8)
        wreg[(size_t)(d * 32 + c4 * 8 + w) * 1024 + slot] = v;
      else
        wlds[((size_t)(d * 8 + c4 * 2 + ((w - 8) >> 2)) * 1024 + slot) * 4 + ((w - 8) & 3)] = v;
    }
  }
}

// ---------------------------------------------------------------------------
// prep: softmax(151), probs->bf16 (padded 192), conf=max(probs[1:]),
// pos = relu(BN(center_size(boxes)) @ pos_w + pos_b), fmaps -> FE bf16.
// FE layout: [enc 0..512 | fmaps 512..2560 | embed 2560..2760 | pos 2760..2888 | pad]
// ---------------------------------------------------------------------------
__global__ void prep_kernel(
    const float* __restrict__ logits, const float* __restrict__ fmaps,
    const float* __restrict__ boxes,
    const float* __restrict__ bn_g, const float* __restrict__ bn_b,
    const float* __restrict__ bn_m, const float* __restrict__ bn_v,
    const float* __restrict__ pos_w, const float* __restrict__ pos_b,
    __hip_bfloat16* __restrict__ FE, __hip_bfloat16* __restrict__ probsb,
    float* __restrict__ conf)
{
  __shared__ float red[256];
  const int row = blockIdx.x, t = threadIdx.x;
  float v = (t < 151) ? logits[(size_t)row * 151 + t] : -3.0e38f;
  red[t] = v; __syncthreads();
  for (int s = 128; s > 0; s >>= 1) { if (t < s) red[t] = fmaxf(red[t], red[t + s]); __syncthreads(); }
  float mx = red[0]; __syncthreads();
  float p = (t < 151) ? expf(v - mx) : 0.f;
  red[t] = p; __syncthreads();
  for (int s = 128; s > 0; s >>= 1) { if (t < s) red[t] += red[t + s]; __syncthreads(); }
  float sum = red[0]; __syncthreads();
  p = p / sum;
  if (t < 192) probsb[(size_t)row * 192 + t] = __float2bfloat16((t < 151) ? p : 0.f);
  red[t] = (t >= 1 && t < 151) ? p : 0.f; __syncthreads();
  for (int s = 128; s > 0; s >>= 1) { if (t < s) red[t] = fmaxf(red[t], red[t + s]); __syncthreads(); }
  if (t == 0) conf[row] = red[0];

  if (t < 128) {
    float x1 = boxes[row * 4 + 0], y1 = boxes[row * 4 + 1];
    float x2 = boxes[row * 4 + 2], y2 = boxes[row * 4 + 3];
    float cs[4] = { (x1 + x2) * 0.5f, (y1 + y2) * 0.5f, x2 - x1, y2 - y1 };
    float a = pos_b[t];
    #pragma unroll
    for (int j = 0; j < 4; j++) {
      float cn = (cs[j] - bn_m[j]) * rsqrtf(bn_v[j] + 1e-5f) * bn_g[j] + bn_b[j];
      a += cn * pos_w[j * 128 + t];
    }
    FE[(size_t)row * FE_LD + 2760 + t] = __float2bfloat16(fmaxf(a, 0.f));
  }
  for (int c0 = t; c0 < 2048; c0 += 256)
    FE[(size_t)row * FE_LD + 512 + c0] = __float2bfloat16(fmaps[(size_t)row * 2048 + c0]);
}

// ---------------------------------------------------------------------------
// Per-image bitonic sort of conf desc (tie: index asc) -> perm (global rows).
// ---------------------------------------------------------------------------
__global__ void sort_kernel(const float* __restrict__ conf, int* __restrict__ perm)
{
  __shared__ float key[128];
  __shared__ int   idx[128];
  const int b = blockIdx.x, t = threadIdx.x;
  key[t] = conf[b * 128 + t]; idx[t] = t;
  __syncthreads();
  for (int k = 2; k <= 128; k <<= 1)
    for (int j = k >> 1; j > 0; j >>= 1) {
      int ixj = t ^ j;
      if (ixj > t) {
        bool up = (t & k) == 0;
        float ka = key[t], kb = key[ixj];
        int ia = idx[t], ib = idx[ixj];
        bool before = (ka > kb) || (ka == kb && ia < ib); // desc, stable
        if (before != up) { key[t] = kb; key[ixj] = ka; idx[t] = ib; idx[ixj] = ia; }
      }
      __syncthreads();
    }
  perm[b * 128 + t] = b * 128 + idx[t];
}

// ---------------------------------------------------------------------------
// LSTM scan, i8 weights, kg-split. 64 blocks = (img 32) x (dir 2), 1024 thr.
// Thread (kg=tid>>8, j=tid&255): int partials of the 4 gates of h-dim j over
// k in [kg*64, kg*64+64). h per thread: 4 b128 broadcasts.
// Weights: 32 u32 resident + 32 u32 LDS (conflict-free stride-16B b128).
// Partials exchanged via int4 part[j*5+kg] — stride-5 padding spreads the
// b128 writes/reads across all 32 banks (R10's stride-4 was 8-way conflict).
// ---------------------------------------------------------------------------
__global__ __launch_bounds__(1024) void rec_kernel(
    const float* __restrict__ P,          // [4096][2048] pre-activations (+bias)
    const int* __restrict__ perm,         // [4096] global rows
    const u32* __restrict__ wreg_g,       // [2][32][1024]
    const uint4* __restrict__ wlds_g,     // [2][8][1024]
    const float* __restrict__ wsc_g,      // [2][1024]
    int gatherPerm, int outPerm,
    __hip_bfloat16* __restrict__ out_bf, int out_ld,
    float* __restrict__ out_f32, int f32_ld, int f32_off)
{
  __shared__ __align__(16) uint4 wt4[8 * 1024];    // 128 KB (k tails per col)
  __shared__ __align__(16) int4 part[256 * 5];     // 20 KB  [j][kg], stride 5
  __shared__ __align__(16) u32 hq[64];             // 256 i8 of h
  __shared__ int prow_lds[128];
  const int tid = threadIdx.x;
  const int kg = tid >> 8;
  const int img = blockIdx.x & 31, dir = blockIdx.x >> 5;

  u32 wv[32];
  {
    const u32* rp = wreg_g + (size_t)dir * 32768 + tid;
    #pragma unroll
    for (int i = 0; i < 32; i++) wv[i] = rp[(size_t)i * 1024];
  }
  #pragma unroll
  for (int i = 0; i < 32; i++) asm volatile("" : "+v"(wv[i]));   // forbid remat
  {
    const uint4* lp = wlds_g + (size_t)dir * 8192 + tid;
    #pragma unroll
    for (int q = 0; q < 8; q++) wt4[q * 1024 + tid] = lp[(size_t)q * 1024];
  }
  if (tid < 128) prow_lds[tid] = perm[img * 128 + tid];
  if (tid < 64) hq[tid] = 0;

  float sc0 = 0.f, sc1 = 0.f, sc2 = 0.f, sc3 = 0.f, cst = 0.f;
  if (tid < 256) {
    const float* sp = wsc_g + dir * 1024 + tid;
    sc0 = sp[0]; sc1 = sp[256]; sc2 = sp[512]; sc3 = sp[768];
  }
  __syncthreads();

  const uint4* hq4 = (const uint4*)hq;

  int st = dir ? 127 : 0;
  float p0 = 0.f, p1 = 0.f, p2 = 0.f, p3 = 0.f;
  if (tid < 256) {
    int prow0 = gatherPerm ? prow_lds[st] : (img * 128 + st);
    const float* pp = P + (size_t)prow0 * 2048 + dir * 1024 + tid;
    p0 = pp[0]; p1 = pp[256]; p2 = pp[512]; p3 = pp[768];
  }

  for (int t = 0; t < 128; t++) {
    float n0 = 0.f, n1 = 0.f, n2 = 0.f, n3 = 0.f;
    if (tid < 256 && t < 127) {
      int stn = dir ? (126 - t) : (t + 1);
      int prn = gatherPerm ? prow_lds[stn] : (img * 128 + stn);
      const float* pp = P + (size_t)prn * 2048 + dir * 1024 + tid;
      n0 = pp[0]; n1 = pp[256]; n2 = pp[512]; n3 = pp[768];
    }

    int a0 = 0, a1 = 0, a2 = 0, a3 = 0;
    // h words 0..7 of this kg chunk : register weights
    #pragma unroll
    for (int hw = 0; hw < 2; hw++) {
      uint4 hv = hq4[kg * 4 + hw];
      #pragma unroll
      for (int s = 0; s < 4; s++) {
        u32 hp = (s == 0) ? hv.x : (s == 1) ? hv.y : (s == 2) ? hv.z : hv.w;
        int w = hw * 4 + s;
        a0 = sdot4(hp, wv[w], a0);
        a1 = sdot4(hp, wv[8 + w], a1);
        a2 = sdot4(hp, wv[16 + w], a2);
        a3 = sdot4(hp, wv[24 + w], a3);
      }
    }
    // h words 8..15 : LDS weights
    #pragma unroll
    for (int half = 0; half < 2; half++) {
      uint4 hv = hq4[kg * 4 + 2 + half];
      uint4 wl = wt4[(half) * 1024 + tid];
      a0 = sdot4(hv.x, wl.x, a0); a0 = sdot4(hv.y, wl.y, a0);
      a0 = sdot4(hv.z, wl.z, a0); a0 = sdot4(hv.w, wl.w, a0);
      wl = wt4[(2 + half) * 1024 + tid];
      a1 = sdot4(hv.x, wl.x, a1); a1 = sdot4(hv.y, wl.y, a1);
      a1 = sdot4(hv.z, wl.z, a1); a1 = sdot4(hv.w, wl.w, a1);
      wl = wt4[(4 + half) * 1024 + tid];
      a2 = sdot4(hv.x, wl.x, a2); a2 = sdot4(hv.y, wl.y, a2);
      a2 = sdot4(hv.z, wl.z, a2); a2 = sdot4(hv.w, wl.w, a2);
      wl = wt4[(6 + half) * 1024 + tid];
      a3 = sdot4(hv.x, wl.x, a3); a3 = sdot4(hv.y, wl.y, a3);
      a3 = sdot4(hv.z, wl.z, a3); a3 = sdot4(hv.w, wl.w, a3);
    }

    part[(tid & 255) * 5 + kg] = int4{a0, a1, a2, a3};
    __syncthreads();

    if (tid < 256) {
      int4 q0 = part[tid * 5 + 0], q1 = part[tid * 5 + 1];
      int4 q2 = part[tid * 5 + 2], q3 = part[tid * 5 + 3];
      float gi = (float)(q0.x + q1.x + q2.x + q3.x) * sc0 + p0;
      float gf = (float)(q0.y + q1.y + q2.y + q3.y) * sc1 + p1;
      float gg = (float)(q0.z + q1.z + q2.z + q3.z) * sc2 + p2;
      float go = (float)(q0.w + q1.w + q2.w + q3.w) * sc3 + p3;
      float si = fsig(gi), sf = fsig(gf), so = fsig(go);
      cst = sf * cst + si * ftanh(gg);
      float h = so * ftanh(cst);
      int qi = __float2int_rn(h * 127.f);
      ((signed char*)hq)[tid] = (signed char)qi;
      const int orow = outPerm ? prow_lds[st] : (img * 128 + st);
      if (out_bf)  out_bf[(size_t)orow * out_ld + dir * 256 + tid] = __float2bfloat16(h);
      if (out_f32) out_f32[(size_t)orow * f32_ld + f32_off + dir * 256 + tid] = h;
    }
    __syncthreads();
    p0 = n0; p1 = n1; p2 = n2; p3 = n3;
    st = dir ? (st - 1) : (st + 1);
  }
}

// ---------------------------------------------------------------------------
// argmax over obj_dists[:,1:151) -> preds (first max wins, like jnp.argmax)
// ---------------------------------------------------------------------------
__global__ void argmax_kernel(const float* __restrict__ dists, int* __restrict__ preds)
{
  const int row = blockIdx.x * 4 + (threadIdx.x >> 6);
  const int lane = threadIdx.x & 63;
  float best = -3.4e38f; int bi = 1000;
  for (int cc = 1 + lane; cc < 151; cc += 64) {
    float v = dists[(size_t)row * 663 + cc];
    if (v > best) { best = v; bi = cc; }
  }
  for (int off = 32; off > 0; off >>= 1) {
    float ov = __shfl_down(best, off);
    int   oi = __shfl_down(bi, off);
    if (ov > best || (ov == best && oi < bi)) { best = ov; bi = oi; }
  }
  if (lane == 0) preds[row] = bi;
}

// ---------------------------------------------------------------------------
// edge_in = [embed2[pred] (200) | enc (512, from FE) | fmaps (2048)] bf16
// ---------------------------------------------------------------------------
__global__ void edge_build(const int* __restrict__ preds,
                           const float* __restrict__ embed2,
                           const float* __restrict__ fmaps,
                           const __hip_bfloat16* __restrict__ FE,
                           __hip_bfloat16* __restrict__ EDGE)
{
  const int row = blockIdx.x, t = threadIdx.x;
  const int pr = preds[row];
  for (int c0 = t; c0 < 200; c0 += 256)
    EDGE[(size_t)row * EDGE_LD + c0] = __float2bfloat16(embed2[(size_t)pr * 200 + c0]);
  for (int c0 = t; c0 < 512; c0 += 256)
    EDGE[(size_t)row * EDGE_LD + 200 + c0] = FE[(size_t)row * FE_LD + c0];
  for (int c0 = t; c0 < 2048; c0 += 256)
    EDGE[(size_t)row * EDGE_LD + 712 + c0] = __float2bfloat16(fmaps[(size_t)row * 2048 + c0]);
}

// ---------------------------------------------------------------------------
extern "C" void kernel_launch(void* const* d_in, const int* in_sizes, int n_in,
                              void* d_out, int out_size, void* d_ws, size_t ws_size,
                              hipStream_t stream)
{
  const float* obj_fmaps    = (const float*)d_in[0];
  const float* obj_logits   = (const float*)d_in[1];
  const float* boxes        = (const float*)d_in[2];
  const float* obj_embed_w  = (const float*)d_in[4];
  const float* obj_embed2_w = (const float*)d_in[5];
  const float* bn_g = (const float*)d_in[6];
  const float* bn_b = (const float*)d_in[7];
  const float* bn_m = (const float*)d_in[8];
  const float* bn_v = (const float*)d_in[9];
  const float* pos_w = (const float*)d_in[10];
  const float* pos_b = (const float*)d_in[11];
  const float* obj_wih0 = (const float*)d_in[12];
  const float* obj_whh0 = (const float*)d_in[13];
  const float* obj_b0   = (const float*)d_in[14];
  const float* obj_wih1 = (const float*)d_in[15];
  const float* obj_whh1 = (const float*)d_in[16];
  const float* obj_b1   = (const float*)d_in[17];
  const float* edge_wih0 = (const float*)d_in[18];
  const float* edge_whh0 = (const float*)d_in[19];
  const float* edge_b0   = (const float*)d_in[20];
  const float* edge_wih1 = (const float*)d_in[21];
  const float* edge_whh1 = (const float*)d_in[22];
  const float* edge_b1   = (const float*)d_in[23];
  const float* dec_w = (const float*)d_in[24];
  const float* dec_b = (const float*)d_in[25];
  float* out = (float*)d_out;

  char* ws = (char*)d_ws;
  auto alloc = [&](size_t bytes) -> char* {
    char* p = ws; ws += (bytes + 255) & ~(size_t)255; return p;
  };
  __hip_bfloat16* FE     = (__hip_bfloat16*)alloc(4096ull * FE_LD * 2);
  __hip_bfloat16* EDGE   = (__hip_bfloat16*)alloc(4096ull * EDGE_LD * 2);
  float*          Pbuf   = (float*)alloc(4096ull * 2048 * 4);
  __hip_bfloat16* hseq   = (__hip_bfloat16*)alloc(4096ull * 512 * 2);
  __hip_bfloat16* probsb = (__hip_bfloat16*)alloc(4096ull * 192 * 2);
  __hip_bfloat16* wih0T  = (__hip_bfloat16*)alloc(2048ull * 2432 * 2);
  __hip_bfloat16* wih1T  = (__hip_bfloat16*)alloc(2048ull * 512 * 2);
  __hip_bfloat16* ewih0T = (__hip_bfloat16*)alloc(2048ull * 2816 * 2);
  __hip_bfloat16* ewih1T = (__hip_bfloat16*)alloc(2048ull * 512 * 2);
  __hip_bfloat16* embedT = (__hip_bfloat16*)alloc(256ull * 192 * 2);
  __hip_bfloat16* decT   = (__hip_bfloat16*)alloc(256ull * 2944 * 2);
  // packed whh set: wreg 65536 u32 | wlds 65536 u32 | wsc 2048 f32
  u32* whh0pk  = (u32*)alloc(133120ull * 4);
  u32* whh1pk  = (u32*)alloc(133120ull * 4);
  u32* ewhh0pk = (u32*)alloc(133120ull * 4);
  u32* ewhh1pk = (u32*)alloc(133120ull * 4);
  int*   perm  = (int*)alloc(4096 * 4);
  float* conf  = (float*)alloc(4096 * 4);
  int*   preds = (int*)alloc(4096 * 4);
  (void)in_sizes; (void)n_in; (void)out_size; (void)ws_size;

  auto tr = [&](const float* src, __hip_bfloat16* dst, int srcK, int srcN,
                int dstR, int dstC, int split, int soff) {
    dim3 g((dstC + 31) / 32, (dstR + 31) / 32);
    transpose_cast<<<g, dim3(256), 0, stream>>>(src, dst, srcK, srcN, dstR, dstC, split, soff);
  };
  for (int d = 0; d < 2; d++) {
    tr(obj_wih0 + (size_t)d * 2376 * 1024, wih0T + (size_t)d * 1024 * 2432, 2376, 1024, 1024, 2432, 0, 0);
    tr(obj_wih1 + (size_t)d * 512 * 1024,  wih1T + (size_t)d * 1024 * 512,  512, 1024, 1024, 512, 0, 0);
    tr(edge_wih0 + (size_t)d * 2760 * 1024, ewih0T + (size_t)d * 1024 * 2816, 2760, 1024, 1024, 2816, 0, 0);
    tr(edge_wih1 + (size_t)d * 512 * 1024,  ewih1T + (size_t)d * 1024 * 512,  512, 1024, 1024, 512, 0, 0);
  }
  tr(obj_embed_w, embedT, 151, 200, 256, 192, 0, 0);
  tr(dec_w, decT, 2888, 151, 256, 2944, 512, 2376);  // [enc|feats] ordering remap

  auto pk = [&](const float* whh, u32* dst) {
    pack_whh<<<dim3(8), dim3(256), 0, stream>>>(whh, dst, dst + 65536, (float*)(dst + 131072));
  };
  pk(obj_whh0, whh0pk); pk(obj_whh1, whh1pk); pk(edge_whh0, ewhh0pk); pk(edge_whh1, ewhh1pk);

  prep_kernel<<<dim3(4096), dim3(256), 0, stream>>>(
      obj_logits, obj_fmaps, boxes, bn_g, bn_b, bn_m, bn_v, pos_w, pos_b, FE, probsb, conf);
  sort_kernel<<<dim3(32), dim3(128), 0, stream>>>(conf, perm);

  auto gemm = [&](const void* A, int lda, const void* B, int ldb, int K, int N,
                  float* oF, __hip_bfloat16* oB, int ldc, const float* bias) {
    dim3 g(32, (N + 127) / 128);
    gemm_kernel<<<g, dim3(256), 0, stream>>>(
        (const u16*)A, lda, (const u16*)B, ldb, K, N, oF, oB, ldc, bias);
  };
  auto rec = [&](const float* P, const u32* wpk, int gat, int op,
                 __hip_bfloat16* ob, int old_, float* of, int fld, int foff) {
    rec_kernel<<<dim3(64), dim3(1024), 0, stream>>>(
        P, perm, wpk, (const uint4*)(wpk + 65536), (const float*)(wpk + 131072),
        gat, op, ob, old_, of, fld, foff);
  };

  // obj_embed -> FE cols [2560,2760)
  gemm(probsb, 192, embedT, 192, 192, 200, nullptr, FE + 2560, FE_LD, nullptr);
  // obj layer 0
  gemm((const u16*)FE + 512, FE_LD, wih0T, 2432, 2432, 2048, Pbuf, nullptr, 2048, obj_b0);
  rec(Pbuf, whh0pk, 1, 0, hseq, 512, nullptr, 0, 0);
  // obj layer 1 -> enc into FE cols [0,512)
  gemm(hseq, 512, wih1T, 512, 512, 2048, Pbuf, nullptr, 2048, obj_b1);
  rec(Pbuf, whh1pk, 0, 1, FE, FE_LD, nullptr, 0, 0);
  // decoder -> out cols [0,151)
  gemm(FE, FE_LD, decT, 2944, 2944, 151, out, nullptr, 663, dec_b);
  argmax_kernel<<<dim3(1024), dim3(256), 0, stream>>>(out, preds);
  edge_build<<<dim3(4096), dim3(256), 0, stream>>>(preds, obj_embed2_w, obj_fmaps, FE, EDGE);
  // edge layer 0
  gemm(EDGE, EDGE_LD, ewih0T, 2816, 2816, 2048, Pbuf, nullptr, 2048, edge_b0);
  rec(Pbuf, ewhh0pk, 1, 0, hseq, 512, nullptr, 0, 0);
  // edge layer 1 -> out cols [151,663)
  gemm(hseq, 512, ewih1T, 512, 512, 2048, Pbuf, nullptr, 2048, edge_b1);
  rec(Pbuf, ewhh1pk, 0, 1, nullptr, 0, out, 663, 151);
}